// Round 24
// baseline (29.375 us; speedup 1.0000x reference)
//
#include <hip/hip_runtime.h>

// NW kernel regression, double-MFMA (attention structure) — r23 skeleton
// (proven 28.2us) with ONE isolated change: EXTENDED LUT over s in [0,3]
// (12290 fp16 entries, 24.6 KB LDS; entries > LUTN are exact 0 = w beyond the
// d=L clamp) so the per-gather fminf disappears on the invL<=1 path (uniform
// in-kernel branch keeps the clamped path for invL>1). Bit-identical output:
// the old fminf path read LUT[4096]=0 for the same keys.
//   MFMA1: fidx = ssL*(|q|^2+|k|^2-2q.k)+0.5 as rank-13 f16 hi/lo GEMM
//   VALU:  w = lut16[(unsigned)fidx]  (lower clamp free via HW cvt_u32 sat)
//   MFMA2: [num|den] = W @ [V|1]  (ch8 = 1.0 denominator column)
// Conventions (proven r12/r14/r15/r17/r18/r19/r23):
//   A-frag 32x32x16: A[row=lane&31][slot=(lane>>5)*8+j]
//   B-frag:          B[slot=(lane>>5)*8+j][col=lane&31]
//   D:               col=lane&31, row=(reg&3)+8*(reg>>2)+4*(lane>>5)
//   vfrag key perm(g,j)=(j&3)+8*(j>>2)+4*g (+16 for set b), folded in prep.

typedef _Float16 h8 __attribute__((ext_vector_type(8)));
typedef float f32x16 __attribute__((ext_vector_type(16)));
typedef float f32x4 __attribute__((ext_vector_type(4)));

#define NCH 8
#define TPB 512        // 8 waves
#define QPB 256        // 8 waves x 32 query-rows
#define KSB 512        // keys per split = 16 tiles of 32
#define NTILE (KSB / 32)
#define LUTN 4096      // cells per unit s
#define LUTX (3 * LUTN + 2)    // extended domain s in [0,3] (d^2 <= 3 for unit cube)
#define LUTXPAD 12296  // pad to multiple of 8 halves (16 B); 24592 B LDS

struct TrueT  { static constexpr bool value = true; };
struct FalseT { static constexpr bool value = false; };

__device__ __forceinline__ float nw_weight_exact(float cd) {
    float r  = __builtin_amdgcn_fractf(cd);
    float sn = __builtin_amdgcn_sinf(r);
    float cs = __builtin_amdgcn_cosf(r);
    float t  = (1.0f - cd) * (1.0f / 3.0f);
    float wt = fmaf(sn, 0.15915494309189535f, fmaf(cs, t, t + t));
    return fmaxf(wt, 0.0f);
}

__device__ __forceinline__ void split16(float x, _Float16& h, _Float16& l) {
    h = (_Float16)x;
    l = (_Float16)(x - (float)h);
}

// kfrag[key*2+g][j]: A-side slots; vfrag[(tile*2+set)*64+lane]: B-side V-frags;
// lutg: extended fp16 LUT (idx<=LUTN: w(sqrt(idx/LUTN)); idx>LUTN: exact 0)
__global__ __launch_bounds__(256) void nw_prep(const float* __restrict__ k,
                                               const float* __restrict__ v,
                                               const float* __restrict__ kl,
                                               h8* __restrict__ kfrag,
                                               h8* __restrict__ vfrag,
                                               _Float16* __restrict__ lutg,
                                               int M) {
    const int idx = blockIdx.x * 256 + threadIdx.x;
    const float iL = 1.0f / kl[0];
    const float ssL = iL * iL * (float)LUTN;
    if (idx < LUTXPAD) {
        lutg[idx] = (idx <= LUTN)
            ? (_Float16)nw_weight_exact(__builtin_amdgcn_sqrtf((float)idx * (1.0f / (float)LUTN)))
            : (_Float16)0.0f;
    }
    if (idx < M) {
        const float x = k[(size_t)idx * 3 + 0];
        const float y = k[(size_t)idx * 3 + 1];
        const float z = k[(size_t)idx * 3 + 2];
        const float cx = -2.0f * ssL * x, cy = -2.0f * ssL * y, cz = -2.0f * ssL * z;
        const float k2 = ssL * fmaf(x, x, fmaf(y, y, z * z));
        _Float16 cxh, cxl, cyh, cyl, czh, czl, k2h, k2l;
        split16(cx, cxh, cxl); split16(cy, cyh, cyl);
        split16(cz, czh, czl); split16(k2, k2h, k2l);
        h8 lo = {cxh, cxh, cxl, cyh, cyh, cyl, czh, czh};
        h8 hi = {czl, k2h, k2l, (_Float16)1.0f, (_Float16)1.0f,
                 (_Float16)0.0f, (_Float16)0.0f, (_Float16)0.0f};
        kfrag[idx * 2 + 0] = lo;
        kfrag[idx * 2 + 1] = hi;
    }
    const int nv = (M / 32) * 128;   // tiles * 2 sets * 64 lanes
    if (idx < nv) {
        const int t = idx >> 7, r = idx & 127;
        const int set = r >> 6, l = r & 63;
        const int ch = l & 31, g = l >> 5;
        h8 o;
#pragma unroll
        for (int j = 0; j < 8; ++j) {
            const int key = t * 32 + set * 16 + ((j & 3) + 8 * (j >> 2) + 4 * g);
            const float val = (ch < 8) ? v[(size_t)key * 8 + ch]
                                       : (ch == 8 ? 1.0f : 0.0f);
            o[j] = (_Float16)val;
        }
        vfrag[(size_t)(t * 2 + set) * 64 + l] = o;
    }
}

__global__ __launch_bounds__(TPB) void nw_main(const float* __restrict__ q,
                                               const h8* __restrict__ kfrag,
                                               const h8* __restrict__ vfrag,
                                               const _Float16* __restrict__ lutg,
                                               const float* __restrict__ kl,
                                               float* __restrict__ part,
                                               int N) {
    __shared__ _Float16 lutw16[LUTXPAD];   // 24.6 KB extended fp16 LUT

    const int tid  = threadIdx.x;
    const int lane = tid & 63;
    const int wid  = tid >> 6;
    const int qg   = blockIdx.x;
    const int sb   = blockIdx.y;

    // stage LUT global -> LDS: 1537 uint4, ~3 per thread
    {
        const uint4* g4 = (const uint4*)lutg;
        uint4* s4 = (uint4*)lutw16;
        for (int e = tid; e < LUTXPAD / 8; e += TPB) s4[e] = g4[e];
    }
    __syncthreads();

    const float iL = 1.0f / kl[0];
    const float ssL = iL * iL * (float)LUTN;

    const int row = lane & 31;
    const int g   = lane >> 5;
    const int qi  = qg * QPB + wid * 32 + row;
    const float qx = q[qi * 3 + 0];
    const float qy = q[qi * 3 + 1];
    const float qz = q[qi * 3 + 2];
    const float q2 = ssL * fmaf(qx, qx, fmaf(qy, qy, qz * qz)) + 0.5f;

    _Float16 qxh, qxl, qyh, qyl, qzh, qzl, q2h, q2l;
    split16(qx, qxh, qxl); split16(qy, qyh, qyl);
    split16(qz, qzh, qzl); split16(q2, q2h, q2l);
    const _Float16 one = (_Float16)1.0f, zer = (_Float16)0.0f;
    // B-frag (constant across tiles): g=0 slots0..7, g=1 slots8..15
    h8 qf;
    qf[0] = g ? qzh : qxh;
    qf[1] = g ? one : qxl;
    qf[2] = g ? one : qxh;
    qf[3] = g ? q2h : qyh;
    qf[4] = g ? q2l : qyl;
    qf[5] = g ? zer : qyh;
    qf[6] = g ? zer : qzh;
    qf[7] = g ? zer : qzl;

    const h8* __restrict__ kfq = kfrag + (size_t)(sb * KSB) * 2;
    const h8* __restrict__ vfq = vfrag + (size_t)(sb * NTILE) * 128;

    f32x16 acc;
#pragma unroll
    for (int e = 0; e < 16; ++e) acc[e] = 0.0f;
    f32x16 zacc;
#pragma unroll
    for (int e = 0; e < 16; ++e) zacc[e] = 0.0f;

    auto tile_loop = [&](auto clampv) {
        constexpr bool CLAMP = decltype(clampv)::value;
        h8 ka  = kfq[(size_t)row * 2 + g];
        h8 vfa = vfq[lane];
        h8 vfb = vfq[64 + lane];
        for (int t = 0; t < NTILE; ++t) {
            const int tn = (t + 1 < NTILE) ? t + 1 : t;
            const h8 ka_n  = kfq[(size_t)(tn * 32 + row) * 2 + g];
            const h8 vfa_n = vfq[(size_t)(tn * 2 + 0) * 64 + lane];
            const h8 vfb_n = vfq[(size_t)(tn * 2 + 1) * 64 + lane];

            const f32x16 s =
                __builtin_amdgcn_mfma_f32_32x32x16_f16(ka, qf, zacc, 0, 0, 0);

            h8 afa, afb;
#pragma unroll
            for (int r = 0; r < 8; ++r) {
                float fx = s[r];
                if constexpr (CLAMP) fx = fminf(fx, (float)(LUTX - 2));
                afa[r] = lutw16[(unsigned)fx];   // ds_read_u16; low clamp = HW sat
            }
#pragma unroll
            for (int r = 0; r < 8; ++r) {
                float fx = s[8 + r];
                if constexpr (CLAMP) fx = fminf(fx, (float)(LUTX - 2));
                afb[r] = lutw16[(unsigned)fx];
            }
            acc = __builtin_amdgcn_mfma_f32_32x32x16_f16(afa, vfa, acc, 0, 0, 0);
            acc = __builtin_amdgcn_mfma_f32_32x32x16_f16(afb, vfb, acc, 0, 0, 0);

            ka = ka_n; vfa = vfa_n; vfb = vfb_n;
        }
    };
    // fast path valid when max fidx = 3*ssL + 0.5 fits the extended table,
    // i.e. invL <= 1 (true for the harness L=1); else keep the clamped path.
    if (ssL <= (float)LUTN) tile_loop(FalseT{});
    else                    tile_loop(TrueT{});

    // D: col=lane&31=channel, row=(reg&3)+8*(reg>>2)+4*g = local query
    const int ch = lane & 31;
    if (ch < 9) {
#pragma unroll
        for (int rq = 0; rq < 4; ++rq) {
            f32x4 o = {acc[4 * rq + 0], acc[4 * rq + 1], acc[4 * rq + 2], acc[4 * rq + 3]};
            const int gi = qg * QPB + wid * 32 + 8 * rq + 4 * g;
            *(f32x4*)(part + ((size_t)sb * 10 + ch) * N + gi) = o;
        }
    }
}

// out[i,c] = (sum_sb num) / (sum_sb den) + 1e-6
// grid: x = N/256 query-chunks, y = NCH channels; coalesced, ascending sb.
__global__ __launch_bounds__(256) void nw_reduce(const float* __restrict__ part,
                                                 float* __restrict__ out,
                                                 int N, int nsb) {
    const int i = blockIdx.x * 256 + threadIdx.x;
    const int c = blockIdx.y;
    if (i >= N) return;
    float s = 0.0f, d = 0.0f;
    for (int sb = 0; sb < nsb; ++sb) {
        const float* base = part + (size_t)sb * 10 * N;
        s += base[(size_t)c * N + i];
        d += base[8 * (size_t)N + i];
    }
    out[(size_t)i * NCH + c] = fmaf(s, 1.0f / d, 1e-6f);
}

// generic fallback: one thread per query over all keys (exact math)
__global__ __launch_bounds__(256) void nw_full(const float* __restrict__ q,
                                               const float* __restrict__ k,
                                               const float* __restrict__ v,
                                               const float* __restrict__ kl,
                                               float* __restrict__ out,
                                               int N, int M) {
    const int i = blockIdx.x * 256 + threadIdx.x;
    if (i >= N) return;
    const float qx = q[i * 3 + 0], qy = q[i * 3 + 1], qz = q[i * 3 + 2];
    const float invL = 1.0f / kl[0];
    float num[NCH];
#pragma unroll
    for (int c = 0; c < NCH; ++c) num[c] = 0.0f;
    float den = 0.0f;
    for (int j = 0; j < M; ++j) {
        float dx = qx - k[j * 3 + 0], dy = qy - k[j * 3 + 1], dz = qz - k[j * 3 + 2];
        float d2 = fmaf(dx, dx, fmaf(dy, dy, dz * dz));
        float wt = nw_weight_exact(__builtin_amdgcn_sqrtf(d2) * invL);
        den += wt;
#pragma unroll
        for (int c = 0; c < NCH; ++c) num[c] = fmaf(wt, v[j * NCH + c], num[c]);
    }
    const float rden = 1.0f / den;
#pragma unroll
    for (int c = 0; c < NCH; ++c) out[i * NCH + c] = fmaf(num[c], rden, 1e-6f);
}

extern "C" void kernel_launch(void* const* d_in, const int* in_sizes, int n_in,
                              void* d_out, int out_size, void* d_ws, size_t ws_size,
                              hipStream_t stream) {
    const float* q  = (const float*)d_in[0];
    const float* k  = (const float*)d_in[1];
    const float* v  = (const float*)d_in[2];
    const float* kl = (const float*)d_in[3];
    float* out = (float*)d_out;

    const int N = in_sizes[0] / 3;   // 8192 queries
    const int M = in_sizes[1] / 3;   // 8192 keys

    const int nsb = (M + KSB - 1) / KSB;
    const size_t part_sz  = (size_t)nsb * 10 * N * sizeof(float);
    const size_t kfrag_sz = (size_t)M * 2 * sizeof(h8);
    const size_t vfrag_sz = (size_t)(M / 32) * 128 * sizeof(h8);
    const size_t lut_sz   = (size_t)LUTXPAD * sizeof(_Float16);

    if ((N % QPB) == 0 && (M % KSB) == 0 &&
        ws_size >= part_sz + kfrag_sz + vfrag_sz + lut_sz) {
        float*    part  = (float*)d_ws;
        h8*       kfrag = (h8*)((char*)d_ws + part_sz);
        h8*       vfrag = (h8*)((char*)d_ws + part_sz + kfrag_sz);
        _Float16* lutg  = (_Float16*)((char*)d_ws + part_sz + kfrag_sz + vfrag_sz);
        const int nprep = (M / 32) * 128;   // >= M, >= LUTXPAD
        nw_prep<<<(nprep + 255) / 256, 256, 0, stream>>>(k, v, kl, kfrag, vfrag, lutg, M);
        dim3 grid(N / QPB, nsb);
        nw_main<<<grid, TPB, 0, stream>>>(q, kfrag, vfrag, lutg, kl, part, N);
        dim3 rgrid((N + 255) / 256, NCH);
        nw_reduce<<<rgrid, 256, 0, stream>>>(part, out, N, nsb);
    } else {
        nw_full<<<(N + 255) / 256, 256, 0, stream>>>(q, k, v, kl, out, N, M);
    }
}

// Round 25
// 28.945 us; speedup vs baseline: 1.0149x; 1.0149x over previous
//
#include <hip/hip_runtime.h>

// NW kernel regression, double-MFMA (attention structure) — FINAL (r23 config,
// proven 28.2us best; r24's extended LUT reverted: staging cost > clamp saving).
//   MFMA1: fidx = ssL*(|q|^2+|k|^2-2q.k)+0.5 as rank-13 f16 hi/lo GEMM
//   VALU:  w = lut16[min(fidx, LUTN)]  (fp16 NN LUT; lower clamp free via HW
//          cvt_u32 saturation)
//   MFMA2: [num|den] = W @ [V|1]  (ch8 = 1.0 denominator column)
// LUT built once in nw_prep (fp16), block-copied via uint4 (513 loads).
// Conventions (proven r12/r14/r15/r17/r18/r19/r23):
//   A-frag 32x32x16: A[row=lane&31][slot=(lane>>5)*8+j]
//   B-frag:          B[slot=(lane>>5)*8+j][col=lane&31]
//   D:               col=lane&31, row=(reg&3)+8*(reg>>2)+4*(lane>>5)
//   vfrag key perm(g,j)=(j&3)+8*(j>>2)+4*g (+16 for set b), folded in prep.
// Ceiling: 1.05M wave-gathers -> ~43K LDS cycles/CU ~= 18us main; aux ~10us
// (fence-fused epilogue thrashes L2 — r20; mega-block r21, pipeline r22,
// TPB256 r16, ext-LUT r24 all measured worse).

typedef _Float16 h8 __attribute__((ext_vector_type(8)));
typedef float f32x16 __attribute__((ext_vector_type(16)));
typedef float f32x4 __attribute__((ext_vector_type(4)));

#define NCH 8
#define TPB 512        // 8 waves
#define QPB 256        // 8 waves x 32 query-rows
#define KSB 512        // keys per split = 16 tiles of 32
#define NTILE (KSB / 32)
#define LUTN 4096
#define LUTPAD 4104    // halves; 8208 B = 513 x uint4

__device__ __forceinline__ float nw_weight_exact(float cd) {
    float r  = __builtin_amdgcn_fractf(cd);
    float sn = __builtin_amdgcn_sinf(r);
    float cs = __builtin_amdgcn_cosf(r);
    float t  = (1.0f - cd) * (1.0f / 3.0f);
    float wt = fmaf(sn, 0.15915494309189535f, fmaf(cs, t, t + t));
    return fmaxf(wt, 0.0f);
}

__device__ __forceinline__ void split16(float x, _Float16& h, _Float16& l) {
    h = (_Float16)x;
    l = (_Float16)(x - (float)h);
}

// kfrag[key*2+g][j]: A-side slots; vfrag[(tile*2+set)*64+lane]: B-side V-frags;
// lutg: fp16 LUT (built once here, copied to LDS by every main block)
__global__ __launch_bounds__(256) void nw_prep(const float* __restrict__ k,
                                               const float* __restrict__ v,
                                               const float* __restrict__ kl,
                                               h8* __restrict__ kfrag,
                                               h8* __restrict__ vfrag,
                                               _Float16* __restrict__ lutg,
                                               int M) {
    const int idx = blockIdx.x * 256 + threadIdx.x;
    const float iL = 1.0f / kl[0];
    const float ssL = iL * iL * (float)LUTN;
    if (idx < LUTPAD) {
        lutg[idx] = (idx <= LUTN)
            ? (_Float16)nw_weight_exact(__builtin_amdgcn_sqrtf((float)idx * (1.0f / (float)LUTN)))
            : (_Float16)0.0f;
    }
    if (idx < M) {
        const float x = k[(size_t)idx * 3 + 0];
        const float y = k[(size_t)idx * 3 + 1];
        const float z = k[(size_t)idx * 3 + 2];
        const float cx = -2.0f * ssL * x, cy = -2.0f * ssL * y, cz = -2.0f * ssL * z;
        const float k2 = ssL * fmaf(x, x, fmaf(y, y, z * z));
        _Float16 cxh, cxl, cyh, cyl, czh, czl, k2h, k2l;
        split16(cx, cxh, cxl); split16(cy, cyh, cyl);
        split16(cz, czh, czl); split16(k2, k2h, k2l);
        h8 lo = {cxh, cxh, cxl, cyh, cyh, cyl, czh, czh};
        h8 hi = {czl, k2h, k2l, (_Float16)1.0f, (_Float16)1.0f,
                 (_Float16)0.0f, (_Float16)0.0f, (_Float16)0.0f};
        kfrag[idx * 2 + 0] = lo;
        kfrag[idx * 2 + 1] = hi;
    }
    const int nv = (M / 32) * 128;   // tiles * 2 sets * 64 lanes
    if (idx < nv) {
        const int t = idx >> 7, r = idx & 127;
        const int set = r >> 6, l = r & 63;
        const int ch = l & 31, g = l >> 5;
        h8 o;
#pragma unroll
        for (int j = 0; j < 8; ++j) {
            const int key = t * 32 + set * 16 + ((j & 3) + 8 * (j >> 2) + 4 * g);
            const float val = (ch < 8) ? v[(size_t)key * 8 + ch]
                                       : (ch == 8 ? 1.0f : 0.0f);
            o[j] = (_Float16)val;
        }
        vfrag[(size_t)(t * 2 + set) * 64 + l] = o;
    }
}

__global__ __launch_bounds__(TPB) void nw_main(const float* __restrict__ q,
                                               const h8* __restrict__ kfrag,
                                               const h8* __restrict__ vfrag,
                                               const _Float16* __restrict__ lutg,
                                               const float* __restrict__ kl,
                                               float* __restrict__ part,
                                               int N) {
    __shared__ _Float16 lutw16[LUTPAD];   // 8.2 KB fp16 LUT

    const int tid  = threadIdx.x;
    const int lane = tid & 63;
    const int wid  = tid >> 6;
    const int qg   = blockIdx.x;
    const int sb   = blockIdx.y;

    // stage LUT global -> LDS: 513 uint4, ~1 per thread
    {
        const uint4* g4 = (const uint4*)lutg;
        uint4* s4 = (uint4*)lutw16;
        for (int e = tid; e < LUTPAD / 8; e += TPB) s4[e] = g4[e];
    }
    __syncthreads();

    const float iL = 1.0f / kl[0];
    const float ssL = iL * iL * (float)LUTN;

    const int row = lane & 31;
    const int g   = lane >> 5;
    const int qi  = qg * QPB + wid * 32 + row;
    const float qx = q[qi * 3 + 0];
    const float qy = q[qi * 3 + 1];
    const float qz = q[qi * 3 + 2];
    const float q2 = ssL * fmaf(qx, qx, fmaf(qy, qy, qz * qz)) + 0.5f;

    _Float16 qxh, qxl, qyh, qyl, qzh, qzl, q2h, q2l;
    split16(qx, qxh, qxl); split16(qy, qyh, qyl);
    split16(qz, qzh, qzl); split16(q2, q2h, q2l);
    const _Float16 one = (_Float16)1.0f, zer = (_Float16)0.0f;
    // B-frag (constant across tiles): g=0 slots0..7, g=1 slots8..15
    h8 qf;
    qf[0] = g ? qzh : qxh;
    qf[1] = g ? one : qxl;
    qf[2] = g ? one : qxh;
    qf[3] = g ? q2h : qyh;
    qf[4] = g ? q2l : qyl;
    qf[5] = g ? zer : qyh;
    qf[6] = g ? zer : qzh;
    qf[7] = g ? zer : qzl;

    const h8* __restrict__ kfq = kfrag + (size_t)(sb * KSB) * 2;
    const h8* __restrict__ vfq = vfrag + (size_t)(sb * NTILE) * 128;

    f32x16 acc;
#pragma unroll
    for (int e = 0; e < 16; ++e) acc[e] = 0.0f;
    f32x16 zacc;
#pragma unroll
    for (int e = 0; e < 16; ++e) zacc[e] = 0.0f;

    // tile-0 operands
    h8 ka  = kfq[(size_t)row * 2 + g];
    h8 vfa = vfq[lane];
    h8 vfb = vfq[64 + lane];

    for (int t = 0; t < NTILE; ++t) {
        const int tn = (t + 1 < NTILE) ? t + 1 : t;
        const h8 ka_n  = kfq[(size_t)(tn * 32 + row) * 2 + g];
        const h8 vfa_n = vfq[(size_t)(tn * 2 + 0) * 64 + lane];
        const h8 vfb_n = vfq[(size_t)(tn * 2 + 1) * 64 + lane];

        const f32x16 s = __builtin_amdgcn_mfma_f32_32x32x16_f16(ka, qf, zacc, 0, 0, 0);

        h8 afa, afb;
#pragma unroll
        for (int r = 0; r < 8; ++r) {
            const float fx = fminf(s[r], (float)LUTN);      // lower clamp: HW cvt sat
            afa[r] = lutw16[(unsigned)fx];                  // ds_read_u16
        }
#pragma unroll
        for (int r = 0; r < 8; ++r) {
            const float fx = fminf(s[8 + r], (float)LUTN);
            afb[r] = lutw16[(unsigned)fx];
        }
        acc = __builtin_amdgcn_mfma_f32_32x32x16_f16(afa, vfa, acc, 0, 0, 0);
        acc = __builtin_amdgcn_mfma_f32_32x32x16_f16(afb, vfb, acc, 0, 0, 0);

        ka = ka_n; vfa = vfa_n; vfb = vfb_n;
    }

    // D: col=lane&31=channel, row=(reg&3)+8*(reg>>2)+4*g = local query
    const int ch = lane & 31;
    if (ch < 9) {
#pragma unroll
        for (int rq = 0; rq < 4; ++rq) {
            f32x4 o = {acc[4 * rq + 0], acc[4 * rq + 1], acc[4 * rq + 2], acc[4 * rq + 3]};
            const int gi = qg * QPB + wid * 32 + 8 * rq + 4 * g;
            *(f32x4*)(part + ((size_t)sb * 10 + ch) * N + gi) = o;
        }
    }
}

// out[i,c] = (sum_sb num) / (sum_sb den) + 1e-6
// grid: x = N/256 query-chunks, y = NCH channels; coalesced, ascending sb.
__global__ __launch_bounds__(256) void nw_reduce(const float* __restrict__ part,
                                                 float* __restrict__ out,
                                                 int N, int nsb) {
    const int i = blockIdx.x * 256 + threadIdx.x;
    const int c = blockIdx.y;
    if (i >= N) return;
    float s = 0.0f, d = 0.0f;
    for (int sb = 0; sb < nsb; ++sb) {
        const float* base = part + (size_t)sb * 10 * N;
        s += base[(size_t)c * N + i];
        d += base[8 * (size_t)N + i];
    }
    out[(size_t)i * NCH + c] = fmaf(s, 1.0f / d, 1e-6f);
}

// generic fallback: one thread per query over all keys (exact math)
__global__ __launch_bounds__(256) void nw_full(const float* __restrict__ q,
                                               const float* __restrict__ k,
                                               const float* __restrict__ v,
                                               const float* __restrict__ kl,
                                               float* __restrict__ out,
                                               int N, int M) {
    const int i = blockIdx.x * 256 + threadIdx.x;
    if (i >= N) return;
    const float qx = q[i * 3 + 0], qy = q[i * 3 + 1], qz = q[i * 3 + 2];
    const float invL = 1.0f / kl[0];
    float num[NCH];
#pragma unroll
    for (int c = 0; c < NCH; ++c) num[c] = 0.0f;
    float den = 0.0f;
    for (int j = 0; j < M; ++j) {
        float dx = qx - k[j * 3 + 0], dy = qy - k[j * 3 + 1], dz = qz - k[j * 3 + 2];
        float d2 = fmaf(dx, dx, fmaf(dy, dy, dz * dz));
        float wt = nw_weight_exact(__builtin_amdgcn_sqrtf(d2) * invL);
        den += wt;
#pragma unroll
        for (int c = 0; c < NCH; ++c) num[c] = fmaf(wt, v[j * NCH + c], num[c]);
    }
    const float rden = 1.0f / den;
#pragma unroll
    for (int c = 0; c < NCH; ++c) out[i * NCH + c] = fmaf(num[c], rden, 1e-6f);
}

extern "C" void kernel_launch(void* const* d_in, const int* in_sizes, int n_in,
                              void* d_out, int out_size, void* d_ws, size_t ws_size,
                              hipStream_t stream) {
    const float* q  = (const float*)d_in[0];
    const float* k  = (const float*)d_in[1];
    const float* v  = (const float*)d_in[2];
    const float* kl = (const float*)d_in[3];
    float* out = (float*)d_out;

    const int N = in_sizes[0] / 3;   // 8192 queries
    const int M = in_sizes[1] / 3;   // 8192 keys

    const int nsb = (M + KSB - 1) / KSB;
    const size_t part_sz  = (size_t)nsb * 10 * N * sizeof(float);
    const size_t kfrag_sz = (size_t)M * 2 * sizeof(h8);
    const size_t vfrag_sz = (size_t)(M / 32) * 128 * sizeof(h8);
    const size_t lut_sz   = (size_t)LUTPAD * sizeof(_Float16);

    if ((N % QPB) == 0 && (M % KSB) == 0 &&
        ws_size >= part_sz + kfrag_sz + vfrag_sz + lut_sz) {
        float*    part  = (float*)d_ws;
        h8*       kfrag = (h8*)((char*)d_ws + part_sz);
        h8*       vfrag = (h8*)((char*)d_ws + part_sz + kfrag_sz);
        _Float16* lutg  = (_Float16*)((char*)d_ws + part_sz + kfrag_sz + vfrag_sz);
        const int nprep = (M / 32) * 128;   // >= M, >= LUTPAD
        nw_prep<<<(nprep + 255) / 256, 256, 0, stream>>>(k, v, kl, kfrag, vfrag, lutg, M);
        dim3 grid(N / QPB, nsb);
        nw_main<<<grid, TPB, 0, stream>>>(q, kfrag, vfrag, lutg, kl, part, N);
        dim3 rgrid((N + 255) / 256, NCH);
        nw_reduce<<<rgrid, 256, 0, stream>>>(part, out, N, nsb);
    } else {
        nw_full<<<(N + 255) / 256, 256, 0, stream>>>(q, k, v, kl, out, N, M);
    }
}